// Round 12
// baseline (95.108 us; speedup 1.0000x reference)
//
#include <hip/hip_runtime.h>

#define N 1024
#define E 256
#define H 128

typedef _Float16 hv2 __attribute__((ext_vector_type(2)));
typedef _Float16 half_t;

__device__ __forceinline__ float dot2_acc(hv2 a, hv2 b, float c) {
#if __has_builtin(__builtin_amdgcn_fdot2)
    return __builtin_amdgcn_fdot2(a, b, c, false);
#else
    return c + (float)a.x * (float)b.x + (float)a.y * (float)b.y;
#endif
}

__device__ __forceinline__ hv2 relu_add2(hv2 a, hv2 b) {
    hv2 s = a + b;
    hv2 z = (hv2)(_Float16)0.f;
    return __builtin_elementwise_max(s, z);
}

// proj v4 (R11-verified, 91.6us): 8-row amortization. 256 blocks x 512 thr.
__global__ __launch_bounds__(512) void proj_kernel(
    const float* __restrict__ x, const float* __restrict__ P,
    const float* __restrict__ Wq, const float* __restrict__ bq,
    const float* __restrict__ Wk, const float* __restrict__ bk,
    const float* __restrict__ Wc, const float* __restrict__ bc,
    const float* __restrict__ W1, const float* __restrict__ b1,
    half_t* __restrict__ qh, half_t* __restrict__ kh) {
    __shared__ __align__(16) float xs[E];       // next-state embedding
    __shared__ __align__(16) float p_s[8 * E];  // 8 P rows (8 KB)
    __shared__ float pc[4][H];                  // ctx partials by e-quarter
    __shared__ float av[H];                     // b_side + ctx
    __shared__ float sp[4][8][H];               // s partials (16 KB)
    __shared__ float sv[8][H];                  // s combined (4 KB)
    __shared__ float qpp[4][8][H];              // W1 partials (16 KB)

    int b = blockIdx.x, t = threadIdx.x;
    int side = b & 1;               // 0 = q, 1 = k
    int i0 = (b >> 1) * 8;          // first of 8 rows
    int h = t & (H - 1);
    int g = t >> 7;                 // quarter group 0..3

    if (t < 64) ((float4*)xs)[t] = ((const float4*)x)[t];
    ((float4*)p_s)[t] = ((const float4*)(P + i0 * E))[t];  // 512 f4 = 8 rows
    __syncthreads();

    // ctx partial: quarter g covers e in [g*64, g*64+64)
    {
        const float* Wce = Wc + g * 64 * H;
        const float* xg = xs + g * 64;
        float p = 0.f;
#pragma unroll 8
        for (int e = 0; e < 64; ++e) p += xg[e] * Wce[e * H + h];
        pc[g][h] = p;
    }
    __syncthreads();
    if (t < H) {
        float ctxv = fmaxf(pc[0][t] + pc[1][t] + pc[2][t] + pc[3][t] + bc[t], 0.f);
        av[t] = (side ? bk[t] : bq[t]) + ctxv;
    }
    __syncthreads();

    // s partials: 8 rows, e-quarter g covers e in [g*64, g*64+64) of E
    {
        const float* W = (side ? Wk : Wq) + g * 64 * H;
        float acc[8];
#pragma unroll
        for (int r = 0; r < 8; ++r) acc[r] = 0.f;
        for (int e = 0; e < 64; e += 8) {
            float m0 = W[(e + 0) * H + h];
            float m1 = W[(e + 1) * H + h];
            float m2 = W[(e + 2) * H + h];
            float m3 = W[(e + 3) * H + h];
            float m4 = W[(e + 4) * H + h];
            float m5 = W[(e + 5) * H + h];
            float m6 = W[(e + 6) * H + h];
            float m7 = W[(e + 7) * H + h];
#pragma unroll
            for (int r = 0; r < 8; ++r) {
                float4 pa = *(const float4*)&p_s[r * E + g * 64 + e];
                float4 pb = *(const float4*)&p_s[r * E + g * 64 + e + 4];
                acc[r] += pa.x * m0 + pa.y * m1 + pa.z * m2 + pa.w * m3
                        + pb.x * m4 + pb.y * m5 + pb.z * m6 + pb.w * m7;
            }
        }
#pragma unroll
        for (int r = 0; r < 8; ++r) sp[g][r][h] = acc[r];
    }
    __syncthreads();
    // combine: thread (g,h) handles rows 2g, 2g+1
    {
        int r0 = g * 2, r1 = r0 + 1;
        sv[r0][h] = sp[0][r0][h] + sp[1][r0][h] + sp[2][r0][h] + sp[3][r0][h] + av[h];
        sv[r1][h] = sp[0][r1][h] + sp[1][r1][h] + sp[2][r1][h] + sp[3][r1][h] + av[h];
    }
    __syncthreads();

    // W1 partials: rr-quarter g covers rr in [g*32, g*32+32) of the side-half.
    {
        const float* W1c = W1 + (side * H + g * 32) * H;
        float acc[8];
#pragma unroll
        for (int r = 0; r < 8; ++r) acc[r] = 0.f;
        for (int r = 0; r < 32; r += 8) {
            float w0 = W1c[(r + 0) * H + h];
            float w1 = W1c[(r + 1) * H + h];
            float w2 = W1c[(r + 2) * H + h];
            float w3 = W1c[(r + 3) * H + h];
            float w4 = W1c[(r + 4) * H + h];
            float w5 = W1c[(r + 5) * H + h];
            float w6 = W1c[(r + 6) * H + h];
            float w7 = W1c[(r + 7) * H + h];
#pragma unroll
            for (int rr = 0; rr < 8; ++rr) {
                const float* S = &sv[rr][g * 32 + r];
                acc[rr] += S[0] * w0 + S[1] * w1 + S[2] * w2 + S[3] * w3
                         + S[4] * w4 + S[5] * w5 + S[6] * w6 + S[7] * w7;
            }
        }
#pragma unroll
        for (int rr = 0; rr < 8; ++rr) qpp[g][rr][h] = acc[rr];
    }
    __syncthreads();
    // combine & write: thread (g,h) writes rows 2g, 2g+1 (f16)
    {
        float bb = side ? 0.f : b1[h];
        int r0 = g * 2, r1 = r0 + 1;
        float v0 = qpp[0][r0][h] + qpp[1][r0][h] + qpp[2][r0][h] + qpp[3][r0][h] + bb;
        float v1 = qpp[0][r1][h] + qpp[1][r1][h] + qpp[2][r1][h] + qpp[3][r1][h] + bb;
        half_t* O = side ? kh : qh;
        O[(i0 + r0) * H + h] = (half_t)v0;
        O[(i0 + r1) * H + h] = (half_t)v1;
    }
}

// pair v2: same 32x32 triangular tiles (528 blocks), but 128 threads x 8
// outputs each (4i x 2j). Per h8-step: 1 w2 + 2 k + 4 q = 7 ds_read_b128 for
// 8 outputs (was 6 for 4) -> wave-read count per block 384 -> 224 (-42%).
// Thread t: jj = t&15 (j = jj, jj+16), ti0 = t>>4 (i = ti0 + u*8, u 0..3).
// LDS layout/strides identical to verified version (272-B rows).
#define QSTR 136  // halves; 272 B row stride -> conflict-free b128
__global__ __launch_bounds__(128) void pair_kernel(
    const half_t* __restrict__ qh, const half_t* __restrict__ kh,
    const float* __restrict__ W2, const float* __restrict__ b2,
    float* __restrict__ out) {
    int tid = blockIdx.x;
    int bi = (int)((65.0f - sqrtf(4225.0f - 8.0f * (float)tid)) * 0.5f);
    while (bi > 0 && tid < 32 * bi - bi * (bi - 1) / 2) --bi;
    while (tid >= 32 * (bi + 1) - (bi + 1) * bi / 2) ++bi;
    int bj = bi + (tid - (32 * bi - bi * (bi - 1) / 2));

    __shared__ __align__(16) half_t qs[32][QSTR];
    __shared__ __align__(16) half_t ks[32][QSTR];
    __shared__ __align__(16) half_t w2s[H];

    int t = threadIdx.x;
    w2s[t] = (half_t)W2[t];  // t 0..127 covers H exactly

    const float4* qh4 = (const float4*)(qh + bi * 32 * H);
    const float4* kh4 = (const float4*)(kh + bj * 32 * H);
#pragma unroll
    for (int v = 0; v < 4; ++v) {
        int idx = v * 128 + t;           // 0..511 : 32 rows x 16 float4
        int r = idx >> 4, c = idx & 15;
        float4 q = qh4[idx];
        float4 k = kh4[idx];
        *(float4*)&qs[r][c * 8] = q;
        *(float4*)&ks[r][c * 8] = k;
    }
    __syncthreads();

    int jj  = t & 15;   // j = jj, jj + 16
    int ti0 = t >> 4;   // i = ti0 + u*8, u 0..3
    float b2v = b2[0];
    float acc[4][2];
#pragma unroll
    for (int u = 0; u < 4; ++u)
#pragma unroll
        for (int v = 0; v < 2; ++v) acc[u][v] = b2v;

    for (int h8 = 0; h8 < 16; ++h8) {
        float4 wf  = *(const float4*)&w2s[h8 * 8];
        float4 kv0 = *(const float4*)&ks[jj][h8 * 8];
        float4 kv1 = *(const float4*)&ks[jj + 16][h8 * 8];
        const hv2* wp  = (const hv2*)&wf;
        const hv2* kp0 = (const hv2*)&kv0;
        const hv2* kp1 = (const hv2*)&kv1;
#pragma unroll
        for (int u = 0; u < 4; ++u) {
            float4 qf = *(const float4*)&qs[ti0 + u * 8][h8 * 8];
            const hv2* qp2 = (const hv2*)&qf;
#pragma unroll
            for (int s = 0; s < 4; ++s) {
                hv2 sa0 = relu_add2(qp2[s], kp0[s]);
                acc[u][0] = dot2_acc(sa0, wp[s], acc[u][0]);
                hv2 sa1 = relu_add2(qp2[s], kp1[s]);
                acc[u][1] = dot2_acc(sa1, wp[s], acc[u][1]);
            }
        }
    }

#pragma unroll
    for (int u = 0; u < 4; ++u) {
#pragma unroll
        for (int v = 0; v < 2; ++v) {
            int i = bi * 32 + ti0 + u * 8;
            int j = bj * 32 + jj + v * 16;
            if (j > i) {
                int base = i * (2 * N - i - 1) / 2;
                out[base + (j - i - 1)] = acc[u][v];
            }
        }
    }
}

extern "C" void kernel_launch(void* const* d_in, const int* in_sizes, int n_in,
                              void* d_out, int out_size, void* d_ws, size_t ws_size,
                              hipStream_t stream) {
    const float* x  = (const float*)d_in[0];
    const float* P  = (const float*)d_in[1];
    const float* Wq = (const float*)d_in[2];
    const float* bq = (const float*)d_in[3];
    const float* Wk = (const float*)d_in[4];
    const float* bk = (const float*)d_in[5];
    const float* Wc = (const float*)d_in[6];
    const float* bc = (const float*)d_in[7];
    const float* W1 = (const float*)d_in[8];
    const float* b1 = (const float*)d_in[9];
    const float* W2 = (const float*)d_in[10];
    const float* b2 = (const float*)d_in[11];
    float* out = (float*)d_out;

    half_t* qh = (half_t*)d_ws;        // 1024*128 halves
    half_t* kh = qh + N * H;           // 1024*128 halves

    proj_kernel<<<256, 512, 0, stream>>>(x, P, Wq, bq, Wk, bk, Wc, bc, W1, b1,
                                         qh, kh);
    pair_kernel<<<528, 128, 0, stream>>>(qh, kh, W2, b2, out);
}

// Round 13
// 91.998 us; speedup vs baseline: 1.0338x; 1.0338x over previous
//
#include <hip/hip_runtime.h>

#define N 1024
#define E 256
#define H 128

typedef _Float16 hv2 __attribute__((ext_vector_type(2)));
typedef _Float16 half_t;

__device__ __forceinline__ float dot2_acc(hv2 a, hv2 b, float c) {
#if __has_builtin(__builtin_amdgcn_fdot2)
    return __builtin_amdgcn_fdot2(a, b, c, false);
#else
    return c + (float)a.x * (float)b.x + (float)a.y * (float)b.y;
#endif
}

__device__ __forceinline__ hv2 relu_add2(hv2 a, hv2 b) {
    hv2 s = a + b;
    hv2 z = (hv2)(_Float16)0.f;
    return __builtin_elementwise_max(s, z);
}

// proj v4 (R11-verified, 91.6us): 8-row amortization. 256 blocks x 512 thr.
__global__ __launch_bounds__(512) void proj_kernel(
    const float* __restrict__ x, const float* __restrict__ P,
    const float* __restrict__ Wq, const float* __restrict__ bq,
    const float* __restrict__ Wk, const float* __restrict__ bk,
    const float* __restrict__ Wc, const float* __restrict__ bc,
    const float* __restrict__ W1, const float* __restrict__ b1,
    half_t* __restrict__ qh, half_t* __restrict__ kh) {
    __shared__ __align__(16) float xs[E];       // next-state embedding
    __shared__ __align__(16) float p_s[8 * E];  // 8 P rows (8 KB)
    __shared__ float pc[4][H];                  // ctx partials by e-quarter
    __shared__ float av[H];                     // b_side + ctx
    __shared__ float sp[4][8][H];               // s partials (16 KB)
    __shared__ float sv[8][H];                  // s combined (4 KB)
    __shared__ float qpp[4][8][H];              // W1 partials (16 KB)

    int b = blockIdx.x, t = threadIdx.x;
    int side = b & 1;               // 0 = q, 1 = k
    int i0 = (b >> 1) * 8;          // first of 8 rows
    int h = t & (H - 1);
    int g = t >> 7;                 // quarter group 0..3

    if (t < 64) ((float4*)xs)[t] = ((const float4*)x)[t];
    ((float4*)p_s)[t] = ((const float4*)(P + i0 * E))[t];  // 512 f4 = 8 rows
    __syncthreads();

    // ctx partial: quarter g covers e in [g*64, g*64+64)
    {
        const float* Wce = Wc + g * 64 * H;
        const float* xg = xs + g * 64;
        float p = 0.f;
#pragma unroll 8
        for (int e = 0; e < 64; ++e) p += xg[e] * Wce[e * H + h];
        pc[g][h] = p;
    }
    __syncthreads();
    if (t < H) {
        float ctxv = fmaxf(pc[0][t] + pc[1][t] + pc[2][t] + pc[3][t] + bc[t], 0.f);
        av[t] = (side ? bk[t] : bq[t]) + ctxv;
    }
    __syncthreads();

    // s partials: 8 rows, e-quarter g covers e in [g*64, g*64+64) of E
    {
        const float* W = (side ? Wk : Wq) + g * 64 * H;
        float acc[8];
#pragma unroll
        for (int r = 0; r < 8; ++r) acc[r] = 0.f;
        for (int e = 0; e < 64; e += 8) {
            float m0 = W[(e + 0) * H + h];
            float m1 = W[(e + 1) * H + h];
            float m2 = W[(e + 2) * H + h];
            float m3 = W[(e + 3) * H + h];
            float m4 = W[(e + 4) * H + h];
            float m5 = W[(e + 5) * H + h];
            float m6 = W[(e + 6) * H + h];
            float m7 = W[(e + 7) * H + h];
#pragma unroll
            for (int r = 0; r < 8; ++r) {
                float4 pa = *(const float4*)&p_s[r * E + g * 64 + e];
                float4 pb = *(const float4*)&p_s[r * E + g * 64 + e + 4];
                acc[r] += pa.x * m0 + pa.y * m1 + pa.z * m2 + pa.w * m3
                        + pb.x * m4 + pb.y * m5 + pb.z * m6 + pb.w * m7;
            }
        }
#pragma unroll
        for (int r = 0; r < 8; ++r) sp[g][r][h] = acc[r];
    }
    __syncthreads();
    // combine: thread (g,h) handles rows 2g, 2g+1
    {
        int r0 = g * 2, r1 = r0 + 1;
        sv[r0][h] = sp[0][r0][h] + sp[1][r0][h] + sp[2][r0][h] + sp[3][r0][h] + av[h];
        sv[r1][h] = sp[0][r1][h] + sp[1][r1][h] + sp[2][r1][h] + sp[3][r1][h] + av[h];
    }
    __syncthreads();

    // W1 partials: rr-quarter g covers rr in [g*32, g*32+32) of the side-half.
    {
        const float* W1c = W1 + (side * H + g * 32) * H;
        float acc[8];
#pragma unroll
        for (int r = 0; r < 8; ++r) acc[r] = 0.f;
        for (int r = 0; r < 32; r += 8) {
            float w0 = W1c[(r + 0) * H + h];
            float w1 = W1c[(r + 1) * H + h];
            float w2 = W1c[(r + 2) * H + h];
            float w3 = W1c[(r + 3) * H + h];
            float w4 = W1c[(r + 4) * H + h];
            float w5 = W1c[(r + 5) * H + h];
            float w6 = W1c[(r + 6) * H + h];
            float w7 = W1c[(r + 7) * H + h];
#pragma unroll
            for (int rr = 0; rr < 8; ++rr) {
                const float* S = &sv[rr][g * 32 + r];
                acc[rr] += S[0] * w0 + S[1] * w1 + S[2] * w2 + S[3] * w3
                         + S[4] * w4 + S[5] * w5 + S[6] * w6 + S[7] * w7;
            }
        }
#pragma unroll
        for (int rr = 0; rr < 8; ++rr) qpp[g][rr][h] = acc[rr];
    }
    __syncthreads();
    // combine & write: thread (g,h) writes rows 2g, 2g+1 (f16)
    {
        float bb = side ? 0.f : b1[h];
        int r0 = g * 2, r1 = r0 + 1;
        float v0 = qpp[0][r0][h] + qpp[1][r0][h] + qpp[2][r0][h] + qpp[3][r0][h] + bb;
        float v1 = qpp[0][r1][h] + qpp[1][r1][h] + qpp[2][r1][h] + qpp[3][r1][h] + bb;
        half_t* O = side ? kh : qh;
        O[(i0 + r0) * H + h] = (half_t)v0;
        O[(i0 + r1) * H + h] = (half_t)v1;
    }
}

// pair v3: exact 512 blocks = 2/CU (was 528 = 2.06/CU -> straggler round).
//  blocks 0..495: off-diag tiles bi<bj, R11-verified 256-thr/4-output body
//    (only the tid->(bi,bj) map changed: strict upper tri,
//     base(bi) = 31*bi - bi*(bi-1)/2).
//  blocks 496..511: TWO diagonal tiles (2d, 2d+1); half-block g=t>>7 covers
//    its 32x32 tile at 8 outputs/thread (both halves together = 4 waves/block,
//    preserving per-CU wave count; R12 showed 2-wave blocks are latency-bound).
//    j>i guard drops the empty lower half.
#define QSTR 136  // halves; 272 B row stride -> conflict-free b128
__global__ __launch_bounds__(256) void pair_kernel(
    const half_t* __restrict__ qh, const half_t* __restrict__ kh,
    const float* __restrict__ W2, const float* __restrict__ b2,
    float* __restrict__ out) {
    __shared__ __align__(16) half_t qs[2][32][QSTR];
    __shared__ __align__(16) half_t ks[2][32][QSTR];
    __shared__ __align__(16) half_t w2s[H];

    int t = threadIdx.x;
    if (t < H) w2s[t] = (half_t)W2[t];
    float b2v = b2[0];

    if (blockIdx.x < 496) {
        // ---------- off-diagonal tile, bi < bj (R11-verified body) ----------
        int tid = blockIdx.x;
        // base(bi) = 31*bi - bi*(bi-1)/2 ; bi0 from quadratic solve
        int bi = (int)((63.0f - sqrtf(3969.0f - 8.0f * (float)tid)) * 0.5f);
        while (bi > 0 && tid < 31 * bi - bi * (bi - 1) / 2) --bi;
        while (tid >= 31 * (bi + 1) - (bi + 1) * bi / 2) ++bi;
        int bj = bi + 1 + (tid - (31 * bi - bi * (bi - 1) / 2));

        const float4* qh4 = (const float4*)(qh + bi * 32 * H);
        const float4* kh4 = (const float4*)(kh + bj * 32 * H);
#pragma unroll
        for (int v = 0; v < 2; ++v) {
            int idx = v * 256 + t;  // 0..511 : 32 rows x 16 float4
            int r = idx >> 4, c = idx & 15;
            float4 q = qh4[idx];
            float4 k = kh4[idx];
            *(float4*)&qs[0][r][c * 8] = q;
            *(float4*)&ks[0][r][c * 8] = k;
        }
        __syncthreads();

        int jj  = t & 31;  // k row within tile
        int ti0 = t >> 5;  // q rows ti0, ti0+8, ti0+16, ti0+24
        float acc[4];
#pragma unroll
        for (int u = 0; u < 4; ++u) acc[u] = b2v;

        for (int h8 = 0; h8 < 16; ++h8) {
            float4 wf = *(const float4*)&w2s[h8 * 8];
            float4 kv = *(const float4*)&ks[0][jj][h8 * 8];
            const hv2* wp = (const hv2*)&wf;
            const hv2* kp2 = (const hv2*)&kv;
#pragma unroll
            for (int u = 0; u < 4; ++u) {
                float4 qf = *(const float4*)&qs[0][ti0 + u * 8][h8 * 8];
                const hv2* qp2 = (const hv2*)&qf;
#pragma unroll
                for (int s = 0; s < 4; ++s) {
                    hv2 sa = relu_add2(qp2[s], kp2[s]);
                    acc[u] = dot2_acc(sa, wp[s], acc[u]);
                }
            }
        }

#pragma unroll
        for (int u = 0; u < 4; ++u) {
            int i = bi * 32 + ti0 + u * 8;
            int j = bj * 32 + jj;
            // bi < bj guarantees j > i; guard kept for safety of diag reuse
            int base = i * (2 * N - i - 1) / 2;
            out[base + (j - i - 1)] = acc[u];
        }
    } else {
        // ---------- two diagonal tiles per block: 2d (g=0), 2d+1 (g=1) ------
        int d = blockIdx.x - 496;       // 0..15
        int g = t >> 7;                 // half-block 0/1
        int lt = t & 127;               // lane within half
        int bt = (2 * d + g) * 32;      // tile base row/col

        const float4* qh4 = (const float4*)(qh + bt * H);
        const float4* kh4 = (const float4*)(kh + bt * H);
#pragma unroll
        for (int v = 0; v < 4; ++v) {
            int idx = v * 128 + lt;     // 0..511 : 32 rows x 16 float4
            int r = idx >> 4, c = idx & 15;
            float4 q = qh4[idx];
            float4 k = kh4[idx];
            *(float4*)&qs[g][r][c * 8] = q;
            *(float4*)&ks[g][r][c * 8] = k;
        }
        __syncthreads();

        int jj  = lt & 15;   // j = jj, jj + 16
        int ti0 = lt >> 4;   // i = ti0 + u*8, u 0..3
        float acc[4][2];
#pragma unroll
        for (int u = 0; u < 4; ++u)
#pragma unroll
            for (int v = 0; v < 2; ++v) acc[u][v] = b2v;

        for (int h8 = 0; h8 < 16; ++h8) {
            float4 wf  = *(const float4*)&w2s[h8 * 8];
            float4 kv0 = *(const float4*)&ks[g][jj][h8 * 8];
            float4 kv1 = *(const float4*)&ks[g][jj + 16][h8 * 8];
            const hv2* wp  = (const hv2*)&wf;
            const hv2* kp0 = (const hv2*)&kv0;
            const hv2* kp1 = (const hv2*)&kv1;
#pragma unroll
            for (int u = 0; u < 4; ++u) {
                float4 qf = *(const float4*)&qs[g][ti0 + u * 8][h8 * 8];
                const hv2* qp2 = (const hv2*)&qf;
#pragma unroll
                for (int s = 0; s < 4; ++s) {
                    hv2 sa0 = relu_add2(qp2[s], kp0[s]);
                    acc[u][0] = dot2_acc(sa0, wp[s], acc[u][0]);
                    hv2 sa1 = relu_add2(qp2[s], kp1[s]);
                    acc[u][1] = dot2_acc(sa1, wp[s], acc[u][1]);
                }
            }
        }

#pragma unroll
        for (int u = 0; u < 4; ++u) {
#pragma unroll
            for (int v = 0; v < 2; ++v) {
                int i = bt + ti0 + u * 8;
                int j = bt + jj + v * 16;
                if (j > i) {
                    int base = i * (2 * N - i - 1) / 2;
                    out[base + (j - i - 1)] = acc[u][v];
                }
            }
        }
    }
}

extern "C" void kernel_launch(void* const* d_in, const int* in_sizes, int n_in,
                              void* d_out, int out_size, void* d_ws, size_t ws_size,
                              hipStream_t stream) {
    const float* x  = (const float*)d_in[0];
    const float* P  = (const float*)d_in[1];
    const float* Wq = (const float*)d_in[2];
    const float* bq = (const float*)d_in[3];
    const float* Wk = (const float*)d_in[4];
    const float* bk = (const float*)d_in[5];
    const float* Wc = (const float*)d_in[6];
    const float* bc = (const float*)d_in[7];
    const float* W1 = (const float*)d_in[8];
    const float* b1 = (const float*)d_in[9];
    const float* W2 = (const float*)d_in[10];
    const float* b2 = (const float*)d_in[11];
    float* out = (float*)d_out;

    half_t* qh = (half_t*)d_ws;        // 1024*128 halves
    half_t* kh = qh + N * H;           // 1024*128 halves

    proj_kernel<<<256, 512, 0, stream>>>(x, P, Wq, bq, Wk, bk, Wc, bc, W1, b1,
                                         qh, kh);
    pair_kernel<<<512, 256, 0, stream>>>(qh, kh, W2, b2, out);
}